// Round 10
// baseline (92.527 us; speedup 1.0000x reference)
//
#include <hip/hip_runtime.h>
#include <hip/hip_fp16.h>

// Problem constants (KANLayer): B=1024, I=128, O=128, H=5
#define Bsz 1024
#define Isz 128
#define Osz 128
#define Hsz 5
#define GB 32    // batches per block
#define NG (Bsz / GB)

// Packed f16 pair: TWO BATCHES per 32-bit VGPR. Splatted f16 param pair fits
// in ONE VGPR (packed f32 needs aligned pairs -> R4/R5 spill storms), so the
// 46-param working set keeps R0's proven allocation.
typedef _Float16 h2 __attribute__((ext_vector_type(2)));

__device__ __forceinline__ h2 lrelu2(h2 v) {
    return __builtin_elementwise_max(v, (h2)((_Float16)0.01f) * v);   // v_pk_mul + v_pk_max
}
__device__ __forceinline__ h2 splat2(float f) {
    const _Float16 h = (_Float16)f;
    h2 r; r.x = h; r.y = h; return r;
}

// ---------------------------------------------------------------------------
// DPP adds. 4 steps (xor1, xor2, row_half_mirror, row_mirror) leave the
// 16-lane-group sum in EVERY lane of each group (rocPRIM-standard property).
// 6 steps (+row_bcast:15/31) leave the full 64-lane sum in lane 63.
// ---------------------------------------------------------------------------
template <int CTRL>
__device__ __forceinline__ float dpp_add(float s) {
    int t = __builtin_amdgcn_update_dpp(0, __builtin_bit_cast(int, s),
                                        CTRL, 0xf, 0xf, true);
    return s + __builtin_bit_cast(float, t);
}
__device__ __forceinline__ float wave_sum16_all(float s) {
    s = dpp_add<0xB1>(s);    // quad_perm [1,0,3,2]  (xor 1)
    s = dpp_add<0x4E>(s);    // quad_perm [2,3,0,1]  (xor 2)
    s = dpp_add<0x141>(s);   // row_half_mirror      (xor 4-equiv)
    s = dpp_add<0x140>(s);   // row_mirror           (xor 8-equiv)
    return s;                // every lane: sum of its 16-lane group
}
__device__ __forceinline__ float wave_sum64_lane63(float s) {
    s = wave_sum16_all(s);
    s = dpp_add<0x142>(s);   // row_bcast:15
    s = dpp_add<0x143>(s);   // row_bcast:31
    return s;                // lane 63 holds the full 64-lane sum
}

// ---------------------------------------------------------------------------
// Edge-stationary kernel, R10. vs R9 (86.9 us):
//  (1) x staged in LDS as PRE-PACKED h2 batch-pairs -> main-loop 'a' is one
//      ds_read_b32 + bitcast (was 2 ds_read + 2 cvt + pack). Same RTE casts.
//  (2) reduce stops at 16-lane groups (4 DPP, no bcast/readlane); 3 cndmask
//      select among the 4 chains and ONE predicated ds_write parks 4 group
//      sums. Final combine sums 8 group-partials (+ per-wave B3 term).
// Per-4-batch stream: ~160 -> ~141 insts. Register shape unchanged.
// ---------------------------------------------------------------------------
__global__ __launch_bounds__(256, 6)
void kan_kernel(const float* __restrict__ x,
                const float* __restrict__ W1, const float* __restrict__ B1,
                const float* __restrict__ W2, const float* __restrict__ B2,
                const float* __restrict__ W3, const float* __restrict__ B3,
                float* __restrict__ out) {
    __shared__ __align__(16) float xsh[GB / 2][Isz];  // 8 KB: h2-packed x pairs
    __shared__ float part2[4][4][GB];                 // 2 KB: [wave][group][batch]
    __shared__ float s3s[4];                          // per-wave B3 row sums

    const int tid = threadIdx.x;
    const int ob  = blockIdx.x & 63;      // o-pair index (fastest)
    const int g   = blockIdx.x >> 6;      // batch group 0..31
    const int b0  = g * GB;
    const int w   = tid >> 6;             // wave 0..3
    const int l   = tid & 63;             // lane
    const int o   = 2 * ob + (w >> 1);    // waves 0,1 -> o0; waves 2,3 -> o1
    const int i   = 64 * (w & 1) + l;     // i-half per wave
    const int e   = o * Isz + i;

    // --- stage x tile as h2 batch-pairs (coalesced float4 reads, once) ---
    {
        const float* xg = x + (size_t)b0 * Isz;
        #pragma unroll
        for (int j = 0; j < 2; ++j) {
            const int g2 = tid + 256 * j;     // 0..511 col-group
            const int r  = g2 >> 5;           // pair-row 0..15
            const int c  = 4 * (g2 & 31);     // col 0..124
            const float4 A = *(const float4*)(xg + (size_t)(2 * r) * Isz + c);
            const float4 Bv = *(const float4*)(xg + (size_t)(2 * r + 1) * Isz + c);
            h2 v0, v1, v2, v3;
            v0.x = (_Float16)A.x;  v0.y = (_Float16)Bv.x;
            v1.x = (_Float16)A.y;  v1.y = (_Float16)Bv.y;
            v2.x = (_Float16)A.z;  v2.y = (_Float16)Bv.z;
            v3.x = (_Float16)A.w;  v3.y = (_Float16)Bv.w;
            float4 wv;
            wv.x = __builtin_bit_cast(float, v0);
            wv.y = __builtin_bit_cast(float, v1);
            wv.z = __builtin_bit_cast(float, v2);
            wv.w = __builtin_bit_cast(float, v3);
            *(float4*)&xsh[r][c] = wv;
        }
    }

    // --- my edge's 46 params -> f16-pair VGPRs (splat both halves), once ---
    h2 w1h[Hsz], b1h[Hsz], w2h[Hsz * Hsz], b2h[Hsz], w3h[Hsz];
    #pragma unroll
    for (int h = 0; h < Hsz; ++h) {
        w1h[h] = splat2(W1[(size_t)e * Hsz + h]);
        b1h[h] = splat2(B1[(size_t)e * Hsz + h]);
        b2h[h] = splat2(B2[(size_t)e * Hsz + h]);
        w3h[h] = splat2(W3[(size_t)e * Hsz + h]);
    }
    #pragma unroll
    for (int j = 0; j < Hsz * Hsz; ++j)
        w2h[j] = splat2(W2[(size_t)e * Hsz * Hsz + j]);

    // batch-invariant b3 term (f32): sum over this wave's 64 i's, once
    {
        const float s3w = wave_sum64_lane63(B3[e]);
        const float s3  = __builtin_bit_cast(float,
            __builtin_amdgcn_readlane(__builtin_bit_cast(int, s3w), 63));
        if (l == 0) s3s[w] = s3;
    }

    __syncthreads();

    #pragma unroll
    for (int bl = 0; bl < GB; bl += 4) {
        // two INDEPENDENT packed chains = 4 batches in flight
        float yv[4];
        #pragma unroll
        for (int u = 0; u < 2; ++u) {
            const h2 a = __builtin_bit_cast(h2, xsh[(bl >> 1) + u][i]);

            // layer 1: scalar -> H, leaky_relu(0.01)
            h2 h1[Hsz];
            #pragma unroll
            for (int h = 0; h < Hsz; ++h)
                h1[h] = lrelu2(__builtin_elementwise_fma(a, w1h[h], b1h[h]));

            // layer 2 (H->H, lrelu) + layer 3 (H->1, b3 hoisted out)
            h2 yy = (h2)(_Float16)0.0f;
            #pragma unroll
            for (int k = 0; k < Hsz; ++k) {
                h2 s = b2h[k];
                #pragma unroll
                for (int h = 0; h < Hsz; ++h)
                    s = __builtin_elementwise_fma(h1[h], w2h[k * Hsz + h], s);
                s = lrelu2(s);
                yy = __builtin_elementwise_fma(s, w3h[k], yy);
            }
            yv[2 * u + 0] = (float)yy.x;
            yv[2 * u + 1] = (float)yy.y;
        }

        // 4-step DPP: every lane gets its 16-lane-group sum, per chain.
        const float g0 = wave_sum16_all(yv[0]);
        const float g1 = wave_sum16_all(yv[1]);
        const float g2 = wave_sum16_all(yv[2]);
        const float g3 = wave_sum16_all(yv[3]);

        // lanes with (l&15)<4 park chain (l&3)'s group sum with ONE ds_write
        const float s01 = (l & 1) ? g1 : g0;
        const float s23 = (l & 1) ? g3 : g2;
        const float val = (l & 2) ? s23 : s01;
        if ((l & 15) < 4)
            part2[w][l >> 4][bl + (l & 3)] = val;
    }

    __syncthreads();

    // combine 2 i-half waves x 4 groups (+ B3 terms); 64 outputs per block
    if (tid < 2 * GB) {
        const int bl = tid & (GB - 1);
        const int oo = tid >> 5;
        float v = s3s[2 * oo] + s3s[2 * oo + 1];
        #pragma unroll
        for (int ww = 0; ww < 2; ++ww)
            #pragma unroll
            for (int gg = 0; gg < 4; ++gg)
                v += part2[2 * oo + ww][gg][bl];
        out[(size_t)(b0 + bl) * Osz + (2 * ob + oo)] = v;
    }
}

extern "C" void kernel_launch(void* const* d_in, const int* in_sizes, int n_in,
                              void* d_out, int out_size, void* d_ws, size_t ws_size,
                              hipStream_t stream) {
    const float* x  = (const float*)d_in[0];
    const float* W1 = (const float*)d_in[1];
    const float* B1 = (const float*)d_in[2];
    const float* W2 = (const float*)d_in[3];
    const float* B2 = (const float*)d_in[4];
    const float* W3 = (const float*)d_in[5];
    const float* B3 = (const float*)d_in[6];
    float* out = (float*)d_out;

    const dim3 grid((Osz / 2) * NG);   // 64 o-pairs x 32 batch groups = 2048 blocks
    kan_kernel<<<grid, dim3(256), 0, stream>>>(x, W1, B1, W2, B2, W3, B3, out);
}

// Round 11
// 87.027 us; speedup vs baseline: 1.0632x; 1.0632x over previous
//
#include <hip/hip_runtime.h>
#include <hip/hip_fp16.h>

// Problem constants (KANLayer): B=1024, I=128, O=128, H=5
#define Bsz 1024
#define Isz 128
#define Osz 128
#define Hsz 5
#define GB 32    // batches per block (16.5 KB LDS -> 6 blocks/CU under (256,6))
#define NG (Bsz / GB)

// Packed f16 pair: TWO BATCHES per 32-bit VGPR. Splatted f16 param pair fits
// in ONE VGPR (unlike packed f32, which needs aligned pairs -> R4/R5 spills),
// so the 46-param working set keeps R0's proven allocation.
// SESSION LESSON (R4/R5/R10): this loop body sits on a register-allocation
// cliff. Structural complications (packed-f32 param pairs, staging repack,
// exec-mask reduce tricks) tip the allocator into VGPR=40 spill-fallback
// (~40 MB scratch WRITE, 2x slowdown). Only shape-preserving edits survive.
typedef _Float16 h2 __attribute__((ext_vector_type(2)));

__device__ __forceinline__ h2 lrelu2(h2 v) {
    return __builtin_elementwise_max(v, (h2)((_Float16)0.01f) * v);   // v_pk_mul + v_pk_max
}
__device__ __forceinline__ h2 splat2(float f) {
    const _Float16 h = (_Float16)f;
    h2 r; r.x = h; r.y = h; return r;
}

// ---------------------------------------------------------------------------
// DPP wave64 sum (f32): quad_perm xor1, xor2, row_half_mirror, row_mirror,
// row_bcast:15, row_bcast:31. Full sum lands in lane 63. All VALU, zero DS.
// ---------------------------------------------------------------------------
template <int CTRL>
__device__ __forceinline__ float dpp_add(float s) {
    int t = __builtin_amdgcn_update_dpp(0, __builtin_bit_cast(int, s),
                                        CTRL, 0xf, 0xf, true);
    return s + __builtin_bit_cast(float, t);
}
__device__ __forceinline__ float wave_sum64_lane63(float s) {
    s = dpp_add<0xB1>(s);    // quad_perm [1,0,3,2]  (xor 1)
    s = dpp_add<0x4E>(s);    // quad_perm [2,3,0,1]  (xor 2)
    s = dpp_add<0x141>(s);   // row_half_mirror      (xor 4)
    s = dpp_add<0x140>(s);   // row_mirror           (xor 8)
    s = dpp_add<0x142>(s);   // row_bcast:15
    s = dpp_add<0x143>(s);   // row_bcast:31
    return s;                // lane 63 holds the full 64-lane sum
}

// ---------------------------------------------------------------------------
// Edge-stationary kernel, R11 = R9 restored (session best, 86.88 us).
// Packed-f16 main loop, two independent pairs (4 batches) in flight; f32
// DPP reduction. R7 counters: VALU-issue-bound (VALUBusy ~100%, zero bank
// conflicts, ~1% HBM). R10's reduce-tax attack spilled (see lesson above);
// this is the proven-stable endpoint.
// ---------------------------------------------------------------------------
__global__ __launch_bounds__(256, 6)
void kan_kernel(const float* __restrict__ x,
                const float* __restrict__ W1, const float* __restrict__ B1,
                const float* __restrict__ W2, const float* __restrict__ B2,
                const float* __restrict__ W3, const float* __restrict__ B3,
                float* __restrict__ out) {
    __shared__ float xs[GB * Isz];        // 16 KB: x[b0:b0+32][0:128]
    __shared__ float partial[4 * GB];     // 512 B: per-wave reduced rows

    const int tid = threadIdx.x;
    const int ob  = blockIdx.x & 63;      // o-pair index (fastest)
    const int g   = blockIdx.x >> 6;      // batch group 0..31
    const int b0  = g * GB;
    const int w   = tid >> 6;             // wave 0..3
    const int l   = tid & 63;             // lane
    const int o   = 2 * ob + (w >> 1);    // waves 0,1 -> o0; waves 2,3 -> o1
    const int i   = 64 * (w & 1) + l;     // i-half per wave
    const int e   = o * Isz + i;

    // --- stage x tile (coalesced float4, once) ---
    {
        const float4* xg = (const float4*)(x + (size_t)b0 * Isz);
        float4* xs4 = (float4*)xs;
        #pragma unroll
        for (int j = 0; j < (GB * Isz / 4) / 256; ++j)   // 4 iters
            xs4[tid + 256 * j] = xg[tid + 256 * j];
    }

    // --- my edge's 46 params -> f16-pair VGPRs (splat both halves), once ---
    h2 w1h[Hsz], b1h[Hsz], w2h[Hsz * Hsz], b2h[Hsz], w3h[Hsz];
    #pragma unroll
    for (int h = 0; h < Hsz; ++h) {
        w1h[h] = splat2(W1[(size_t)e * Hsz + h]);
        b1h[h] = splat2(B1[(size_t)e * Hsz + h]);
        b2h[h] = splat2(B2[(size_t)e * Hsz + h]);
        w3h[h] = splat2(W3[(size_t)e * Hsz + h]);
    }
    #pragma unroll
    for (int j = 0; j < Hsz * Hsz; ++j)
        w2h[j] = splat2(W2[(size_t)e * Hsz * Hsz + j]);

    // batch-invariant b3 term (f32): sum over this wave's 64 i's, once
    const float s3w = wave_sum64_lane63(B3[e]);
    const float s3  = __builtin_bit_cast(float,
        __builtin_amdgcn_readlane(__builtin_bit_cast(int, s3w), 63));

    __syncthreads();

    float res = 0.0f;   // out-partial for batch b0+l (l < GB), this i-half

    #pragma unroll
    for (int bl = 0; bl < GB; bl += 4) {
        // two INDEPENDENT packed chains = 4 batches in flight (ILP as R0)
        float yv[4];
        #pragma unroll
        for (int u = 0; u < 2; ++u) {
            const int bb = bl + 2 * u;
            h2 a;
            a.x = (_Float16)xs[(bb + 0) * Isz + i];
            a.y = (_Float16)xs[(bb + 1) * Isz + i];

            // layer 1: scalar -> H, leaky_relu(0.01)
            h2 h1[Hsz];
            #pragma unroll
            for (int h = 0; h < Hsz; ++h)
                h1[h] = lrelu2(__builtin_elementwise_fma(a, w1h[h], b1h[h]));

            // layer 2 (H->H, lrelu) + layer 3 (H->1, b3 hoisted out)
            h2 yy = (h2)(_Float16)0.0f;
            #pragma unroll
            for (int k = 0; k < Hsz; ++k) {
                h2 s = b2h[k];
                #pragma unroll
                for (int h = 0; h < Hsz; ++h)
                    s = __builtin_elementwise_fma(h1[h], w2h[k * Hsz + h], s);
                s = lrelu2(s);
                yy = __builtin_elementwise_fma(s, w3h[k], yy);
            }
            yv[2 * u + 0] = (float)yy.x;
            yv[2 * u + 1] = (float)yy.y;
        }

        // DPP reduce the 4 chains (f32); park lane-63 totals in their lanes.
        #pragma unroll
        for (int c = 0; c < 4; ++c) {
            const float s = wave_sum64_lane63(yv[c]);
            const float tot = __builtin_bit_cast(float,
                __builtin_amdgcn_readlane(__builtin_bit_cast(int, s), 63));
            if (l == bl + c) res = tot;
        }
    }

    if (l < GB) partial[w * GB + l] = res + s3;
    __syncthreads();

    // combine i-half waves and store: 64 outputs per block, each written once
    if (tid < 2 * GB) {
        const int bl = tid & (GB - 1);
        const int oo = tid >> 5;
        const float v = partial[(2 * oo) * GB + bl] + partial[(2 * oo + 1) * GB + bl];
        out[(size_t)(b0 + bl) * Osz + (2 * ob + oo)] = v;
    }
}

extern "C" void kernel_launch(void* const* d_in, const int* in_sizes, int n_in,
                              void* d_out, int out_size, void* d_ws, size_t ws_size,
                              hipStream_t stream) {
    const float* x  = (const float*)d_in[0];
    const float* W1 = (const float*)d_in[1];
    const float* B1 = (const float*)d_in[2];
    const float* W2 = (const float*)d_in[3];
    const float* B2 = (const float*)d_in[4];
    const float* W3 = (const float*)d_in[5];
    const float* B3 = (const float*)d_in[6];
    float* out = (float*)d_out;

    const dim3 grid((Osz / 2) * NG);   // 64 o-pairs x 32 batch groups = 2048 blocks
    kan_kernel<<<grid, dim3(256), 0, stream>>>(x, W1, B1, W2, B2, W3, B3, out);
}